// Round 1
// baseline (484.011 us; speedup 1.0000x reference)
//
#include <hip/hip_runtime.h>
#include <hip/hip_bf16.h>

// B=4, T=2048, C=1024, H=16, HD=64. JOINED_DIM=25 (mask col%25==24 -> masked).

typedef __attribute__((ext_vector_type(8))) short short8;
typedef __attribute__((ext_vector_type(4))) float floatx4;

__device__ inline unsigned short f2bf(float f){
    union { __hip_bfloat16 h; unsigned short u; } cv;
    cv.h = __float2bfloat16(f);
    return cv.u;
}

// ---------------- fp32 -> bf16 conversion ----------------
__global__ __launch_bounds__(256) void cvt_kernel(const float* __restrict__ in,
                                                  unsigned short* __restrict__ out, int n4){
    int i = blockIdx.x * 256 + threadIdx.x;
    if (i < n4){
        float4 v = reinterpret_cast<const float4*>(in)[i];
        ushort4 o;
        o.x = f2bf(v.x); o.y = f2bf(v.y); o.z = f2bf(v.z); o.w = f2bf(v.w);
        reinterpret_cast<ushort4*>(out)[i] = o;
    }
}

// ---------------- GEMM: C = A @ W^T + bias ----------------
// A: [8192,1024] bf16 row-major; W: [1024,1024] bf16 row-major (torch Linear weight).
// 64x64 tile, BK=64, 256 threads = 4 waves (2x2), each wave 32x32 via 16x16x32 MFMA.
#define MODE_HEAD 0   // write bf16 [B,H,T,HD], val*scale
#define MODE_VT   1   // write bf16 [B,H,HD,T]
#define MODE_OUT  2   // write fp32 [8192,1024]

template<int MODE>
__global__ __launch_bounds__(256) void gemm_bt(
    const unsigned short* __restrict__ A,
    const unsigned short* __restrict__ W,
    const float* __restrict__ bias,
    void* __restrict__ out, float scale)
{
    __shared__ unsigned short lA[64*72];
    __shared__ unsigned short lB[64*72];
    const int tid = threadIdx.x;
    const int lane = tid & 63;
    const int wave = tid >> 6;
    const int lane15 = lane & 15;
    const int quad = lane >> 4;
    const int wm = wave >> 1, wn = wave & 1;
    const int m0 = blockIdx.y * 64;
    const int n0 = blockIdx.x * 64;

    floatx4 zero = {0.f, 0.f, 0.f, 0.f};
    floatx4 acc[2][2];
    acc[0][0] = zero; acc[0][1] = zero; acc[1][0] = zero; acc[1][1] = zero;

    for (int k0 = 0; k0 < 1024; k0 += 64){
        #pragma unroll
        for (int i = 0; i < 2; i++){
            int c = i*256 + tid;
            int row = c >> 3, grp = c & 7;
            uint4 av = *reinterpret_cast<const uint4*>(A + (size_t)(m0+row)*1024 + k0 + grp*8);
            uint4 wv = *reinterpret_cast<const uint4*>(W + (size_t)(n0+row)*1024 + k0 + grp*8);
            *reinterpret_cast<uint4*>(&lA[row*72 + grp*8]) = av;
            *reinterpret_cast<uint4*>(&lB[row*72 + grp*8]) = wv;
        }
        __syncthreads();
        #pragma unroll
        for (int ks = 0; ks < 2; ks++){
            short8 a0 = *reinterpret_cast<const short8*>(&lA[(wm*32 +      lane15)*72 + ks*32 + quad*8]);
            short8 a1 = *reinterpret_cast<const short8*>(&lA[(wm*32 + 16 + lane15)*72 + ks*32 + quad*8]);
            short8 b0 = *reinterpret_cast<const short8*>(&lB[(wn*32 +      lane15)*72 + ks*32 + quad*8]);
            short8 b1 = *reinterpret_cast<const short8*>(&lB[(wn*32 + 16 + lane15)*72 + ks*32 + quad*8]);
            acc[0][0] = __builtin_amdgcn_mfma_f32_16x16x32_bf16(a0, b0, acc[0][0], 0, 0, 0);
            acc[0][1] = __builtin_amdgcn_mfma_f32_16x16x32_bf16(a0, b1, acc[0][1], 0, 0, 0);
            acc[1][0] = __builtin_amdgcn_mfma_f32_16x16x32_bf16(a1, b0, acc[1][0], 0, 0, 0);
            acc[1][1] = __builtin_amdgcn_mfma_f32_16x16x32_bf16(a1, b1, acc[1][1], 0, 0, 0);
        }
        __syncthreads();
    }

    // epilogue: C/D layout col = lane&15, row = quad*4 + reg (m89-verified)
    #pragma unroll
    for (int ti = 0; ti < 2; ti++){
        #pragma unroll
        for (int tj = 0; tj < 2; tj++){
            int n = n0 + wn*32 + tj*16 + lane15;
            float bv = bias[n];
            #pragma unroll
            for (int r = 0; r < 4; r++){
                int m = m0 + wm*32 + ti*16 + quad*4 + r;
                float val = (acc[ti][tj][r] + bv) * scale;
                if (MODE == MODE_OUT){
                    reinterpret_cast<float*>(out)[(size_t)m*1024 + n] = val;
                } else {
                    int b = m >> 11, t = m & 2047;
                    int h = n >> 6,  d = n & 63;
                    unsigned short* o = reinterpret_cast<unsigned short*>(out);
                    if (MODE == MODE_HEAD)
                        o[(((size_t)b*16 + h)*2048 + t)*64 + d] = f2bf(val);
                    else
                        o[(((size_t)b*16 + h)*64 + d)*2048 + t] = f2bf(val);
                }
            }
        }
    }
}

// ---------------- Flash attention ----------------
// grid: (32 q-tiles, 64 bh). block 256 = 4 waves; wave w handles 16 q rows.
// q pre-scaled by 1/sqrt(64). k: [B,H,T,64] bf16. vT: [B,H,64,T] bf16.
__global__ __launch_bounds__(256) void flash_attn(
    const unsigned short* __restrict__ q,
    const unsigned short* __restrict__ k,
    const unsigned short* __restrict__ vT,
    unsigned short* __restrict__ y)
{
    __shared__ unsigned short lK[64*72];
    __shared__ unsigned short lV[64*72];
    __shared__ unsigned short lP[4*16*72];
    const int tid = threadIdx.x;
    const int lane = tid & 63;
    const int wave = tid >> 6;
    const int lane15 = lane & 15;
    const int quad = lane >> 4;
    const int bh = blockIdx.y;
    const int qt = (int)gridDim.x - 1 - (int)blockIdx.x;  // longest blocks dispatch first
    const int r0 = qt*64 + wave*16;                       // global q-row base for this wave

    short8 qf[2];
    #pragma unroll
    for (int f = 0; f < 2; f++)
        qf[f] = *reinterpret_cast<const short8*>(q + ((size_t)bh*2048 + r0 + lane15)*64 + f*32 + quad*8);

    floatx4 zero = {0.f, 0.f, 0.f, 0.f};
    floatx4 acc[4];
    acc[0] = zero; acc[1] = zero; acc[2] = zero; acc[3] = zero;
    float m_i[4], l_i[4];
    #pragma unroll
    for (int r = 0; r < 4; r++){ m_i[r] = -INFINITY; l_i[r] = 0.f; }

    unsigned short* pw = &lP[wave*16*72];

    for (int j0 = 0; j0 <= qt*64; j0 += 64){
        #pragma unroll
        for (int i = 0; i < 2; i++){
            int c = i*256 + tid;
            int row = c >> 3, grp = c & 7;
            *reinterpret_cast<uint4*>(&lK[row*72 + grp*8]) =
                *reinterpret_cast<const uint4*>(k + ((size_t)bh*2048 + j0 + row)*64 + grp*8);
            *reinterpret_cast<uint4*>(&lV[row*72 + grp*8]) =
                *reinterpret_cast<const uint4*>(vT + ((size_t)bh*64 + row)*2048 + j0 + grp*8);
        }
        __syncthreads();

        // S = Q K^T for 16 rows x 64 cols
        floatx4 s[4];
        #pragma unroll
        for (int tj = 0; tj < 4; tj++){
            short8 kf0 = *reinterpret_cast<const short8*>(&lK[(tj*16+lane15)*72 +      quad*8]);
            short8 kf1 = *reinterpret_cast<const short8*>(&lK[(tj*16+lane15)*72 + 32 + quad*8]);
            floatx4 z = zero;
            z = __builtin_amdgcn_mfma_f32_16x16x32_bf16(qf[0], kf0, z, 0, 0, 0);
            z = __builtin_amdgcn_mfma_f32_16x16x32_bf16(qf[1], kf1, z, 0, 0, 0);
            s[tj] = z;
        }

        // mask: causal + RL branch (col % 25 == 24)
        #pragma unroll
        for (int tj = 0; tj < 4; tj++){
            int col = j0 + tj*16 + lane15;
            bool colBad = (col % 25) == 24;
            #pragma unroll
            for (int r = 0; r < 4; r++){
                int rowq = r0 + quad*4 + r;
                if (colBad || col > rowq) s[tj][r] = -INFINITY;
            }
        }

        // online softmax (rows live across the 16 lanes sharing quad)
        float alpha[4];
        #pragma unroll
        for (int r = 0; r < 4; r++){
            float m = fmaxf(fmaxf(s[0][r], s[1][r]), fmaxf(s[2][r], s[3][r]));
            #pragma unroll
            for (int off = 1; off < 16; off <<= 1) m = fmaxf(m, __shfl_xor(m, off));
            float mnew = fmaxf(m_i[r], m);
            alpha[r] = __expf(m_i[r] - mnew);
            m_i[r] = mnew;
            float ls = 0.f;
            #pragma unroll
            for (int tj = 0; tj < 4; tj++){
                float p = __expf(s[tj][r] - mnew);
                s[tj][r] = p;
                ls += p;
            }
            #pragma unroll
            for (int off = 1; off < 16; off <<= 1) ls += __shfl_xor(ls, off);
            l_i[r] = l_i[r]*alpha[r] + ls;
            #pragma unroll
            for (int dt = 0; dt < 4; dt++) acc[dt][r] *= alpha[r];
        }

        // P: C-layout -> LDS -> A-layout (per-wave region)
        #pragma unroll
        for (int tj = 0; tj < 4; tj++)
            #pragma unroll
            for (int r = 0; r < 4; r++)
                pw[(quad*4+r)*72 + tj*16 + lane15] = f2bf(s[tj][r]);
        __syncthreads();

        // O += P V   (B-operand from vT tile: rows are d, k is j contiguous)
        #pragma unroll
        for (int ks = 0; ks < 2; ks++){
            short8 pf = *reinterpret_cast<const short8*>(&pw[lane15*72 + ks*32 + quad*8]);
            #pragma unroll
            for (int dt = 0; dt < 4; dt++){
                short8 vf = *reinterpret_cast<const short8*>(&lV[(dt*16+lane15)*72 + ks*32 + quad*8]);
                acc[dt] = __builtin_amdgcn_mfma_f32_16x16x32_bf16(pf, vf, acc[dt], 0, 0, 0);
            }
        }
        __syncthreads();
    }

    const int b = bh >> 4, h = bh & 15;
    #pragma unroll
    for (int dt = 0; dt < 4; dt++){
        #pragma unroll
        for (int r = 0; r < 4; r++){
            float o = acc[dt][r] / l_i[r];
            int t = r0 + quad*4 + r;
            int cc = h*64 + dt*16 + lane15;
            y[((size_t)b*2048 + t)*1024 + cc] = f2bf(o);
        }
    }
}

// ---------------- launch ----------------
extern "C" void kernel_launch(void* const* d_in, const int* in_sizes, int n_in,
                              void* d_out, int out_size, void* d_ws, size_t ws_size,
                              hipStream_t stream)
{
    const float* x  = (const float*)d_in[0];
    const float* Wq = (const float*)d_in[1];
    const float* bq = (const float*)d_in[2];
    const float* Wk = (const float*)d_in[3];
    const float* bk = (const float*)d_in[4];
    const float* Wv = (const float*)d_in[5];
    const float* bv = (const float*)d_in[6];
    const float* Wp = (const float*)d_in[7];
    const float* bp = (const float*)d_in[8];
    float* out = (float*)d_out;

    unsigned short* ws  = (unsigned short*)d_ws;
    unsigned short* xbf = ws;                       // 8192*1024
    unsigned short* wqb = xbf + (size_t)8192*1024;  // 1024*1024 each
    unsigned short* wkb = wqb + (size_t)1024*1024;
    unsigned short* wvb = wkb + (size_t)1024*1024;
    unsigned short* wpb = wvb + (size_t)1024*1024;
    unsigned short* qws = wpb + (size_t)1024*1024;  // [B,H,T,64]
    unsigned short* kws = qws + (size_t)8388608;    // [B,H,T,64]
    unsigned short* vtw = kws + (size_t)8388608;    // [B,H,64,T]
    unsigned short* yws = vtw + (size_t)8388608;    // [B,T,C]

    cvt_kernel<<<8192, 256, 0, stream>>>(x,  xbf, 2097152);
    cvt_kernel<<<1024, 256, 0, stream>>>(Wq, wqb, 262144);
    cvt_kernel<<<1024, 256, 0, stream>>>(Wk, wkb, 262144);
    cvt_kernel<<<1024, 256, 0, stream>>>(Wv, wvb, 262144);
    cvt_kernel<<<1024, 256, 0, stream>>>(Wp, wpb, 262144);

    dim3 gg(16, 128);
    gemm_bt<MODE_HEAD><<<gg, 256, 0, stream>>>(xbf, wqb, bq, qws, 0.125f);
    gemm_bt<MODE_HEAD><<<gg, 256, 0, stream>>>(xbf, wkb, bk, kws, 1.0f);
    gemm_bt<MODE_VT  ><<<gg, 256, 0, stream>>>(xbf, wvb, bv, vtw, 1.0f);

    flash_attn<<<dim3(32, 64), 256, 0, stream>>>(qws, kws, vtw, yws);

    gemm_bt<MODE_OUT ><<<gg, 256, 0, stream>>>(yws, wpb, bp, out, 1.0f);
}